// Round 4
// baseline (485.570 us; speedup 1.0000x reference)
//
#include <hip/hip_runtime.h>

#define NN 100000
#define NE 3200000
#define BSH 7                 // 128 nodes per bucket
#define BNODES 128
#define NBUCK 782             // ceil(NN/128)
#define BCAP 4800             // mean 4096, sigma 64 -> +11 sigma headroom
#define BIN_CHUNK 8192
#define NBIN_BLOCKS ((NE + BIN_CHUNK - 1) / BIN_CHUNK)   // 391

// ---------------- Layer 1 node transform ----------------
// y1[i]   = x[i] @ W_rel1               (8 wide)
// agg1[i] = x[i] @ W_root1 + b_rel1     (8 wide, init for aggregation)
__global__ void node_layer1(const float* __restrict__ x,
                            const float* __restrict__ Wrel1,
                            const float* __restrict__ brel1,
                            const float* __restrict__ Wroot1,
                            float* __restrict__ y1,
                            float* __restrict__ agg1) {
    __shared__ float sW[16 * 8];
    __shared__ float sR[16 * 8];
    __shared__ float sb[8];
    int t = threadIdx.x;
    if (t < 128) { sW[t] = Wrel1[t]; sR[t] = Wroot1[t]; }
    if (t < 8)   { sb[t] = brel1[t]; }
    __syncthreads();

    int i = blockIdx.x * blockDim.x + t;
    if (i >= NN) return;

    const float4* xp = (const float4*)(x + (size_t)i * 16);
    float4 x0 = xp[0], x1 = xp[1], x2 = xp[2], x3 = xp[3];
    float xi[16] = {x0.x, x0.y, x0.z, x0.w, x1.x, x1.y, x1.z, x1.w,
                    x2.x, x2.y, x2.z, x2.w, x3.x, x3.y, x3.z, x3.w};

    float y[8], r[8];
#pragma unroll
    for (int j = 0; j < 8; ++j) { y[j] = 0.0f; r[j] = sb[j]; }
#pragma unroll
    for (int k = 0; k < 16; ++k) {
        float xv = xi[k];
#pragma unroll
        for (int j = 0; j < 8; ++j) {
            y[j] = fmaf(xv, sW[k * 8 + j], y[j]);
            r[j] = fmaf(xv, sR[k * 8 + j], r[j]);
        }
    }
    float4* yp = (float4*)(y1 + (size_t)i * 8);
    float4* ap = (float4*)(agg1 + (size_t)i * 8);
    yp[0] = make_float4(y[0], y[1], y[2], y[3]);
    yp[1] = make_float4(y[4], y[5], y[6], y[7]);
    ap[0] = make_float4(r[0], r[1], r[2], r[3]);
    ap[1] = make_float4(r[4], r[5], r[6], r[7]);
}

// ---------------- Binning: scatter packed (dstLocal,src) into per-bucket lists ----------------
__global__ __launch_bounds__(512) void binning(const int* __restrict__ src,
                                               const int* __restrict__ dst,
                                               int* __restrict__ bucketCnt,
                                               int* __restrict__ bpay) {
    __shared__ int hist[NBUCK];
    __shared__ int base[NBUCK];
    int t = threadIdx.x;
    int e0 = blockIdx.x * BIN_CHUNK;

    for (int i = t; i < NBUCK; i += 512) hist[i] = 0;
    __syncthreads();

#pragma unroll 4
    for (int k = 0; k < BIN_CHUNK / 512; ++k) {
        int e = e0 + k * 512 + t;
        if (e < NE) atomicAdd(&hist[dst[e] >> BSH], 1);
    }
    __syncthreads();

    for (int i = t; i < NBUCK; i += 512) {
        int c = hist[i];
        base[i] = c ? atomicAdd(&bucketCnt[i], c) : 0;
        hist[i] = 0;   // reuse as cursor
    }
    __syncthreads();

#pragma unroll 2
    for (int k = 0; k < BIN_CHUNK / 512; ++k) {
        int e = e0 + k * 512 + t;
        if (e < NE) {
            int d = dst[e];
            int s = src[e];
            int b = d >> BSH;
            int r = atomicAdd(&hist[b], 1);
            int p = base[b] + r;
            if (p < BCAP) bpay[b * BCAP + p] = ((d & (BNODES - 1)) << 17) | s;
        }
    }
}

// ---------------- Bucket aggregation, layer 1 (LDS ds_add, no sort) ----------------
// h1[n] = relu( agg1_init[n] + sum_{j->n} y1[j] )   (in place: h1 buffer == agg1 buffer)
__global__ __launch_bounds__(256) void bucket_agg1(const int* __restrict__ bucketCnt,
                                                   const int* __restrict__ bpay,
                                                   const float* __restrict__ y1,
                                                   float* __restrict__ h1) {
    __shared__ float facc[BNODES * 8];
    int t = threadIdx.x;
    int b = blockIdx.x;
    int gbase = b * BCAP;
    int fbase = b * (BNODES * 8);

#pragma unroll
    for (int k = t; k < BNODES * 8; k += 256) {
        int gi = fbase + k;
        facc[k] = (gi < NN * 8) ? h1[gi] : 0.0f;
    }
    int C = bucketCnt[b]; if (C > BCAP) C = BCAP;
    __syncthreads();

    int f = t & 7, g = t >> 3;   // 32 edge groups of 8 feature lanes
    for (int e0 = 0; e0 < C; e0 += 64) {
        int e1 = e0 + g, e2 = e1 + 32;
        bool p1 = e1 < C, p2 = e2 < C;
        int v1 = 0, v2 = 0;
        if (p1) v1 = bpay[gbase + e1];
        if (p2) v2 = bpay[gbase + e2];
        if (p1) {
            float val = y1[((v1 & 0x1FFFF) << 3) + f];
            atomicAdd(&facc[((v1 >> 17) << 3) + f], val);
        }
        if (p2) {
            float val = y1[((v2 & 0x1FFFF) << 3) + f];
            atomicAdd(&facc[((v2 >> 17) << 3) + f], val);
        }
    }
    __syncthreads();

    for (int k = t; k < BNODES * 8; k += 256) {
        int gi = fbase + k;
        if (gi < NN * 8) { float v = facc[k]; h1[gi] = v > 0.0f ? v : 0.0f; }
    }
}

// ---------------- Bucket aggregation layer 2 + fused tail ----------------
// agg2 stays in LDS; fused GraphConv2 combine + fc1 + fc2 + gsum accumulation.
__global__ __launch_bounds__(256) void bucket_agg2_tail(const int* __restrict__ bucketCnt,
                                                        const int* __restrict__ bpay,
                                                        const float* __restrict__ h1,
                                                        const float* __restrict__ Wrel2,
                                                        const float* __restrict__ brel2,
                                                        const float* __restrict__ Wroot2,
                                                        const float* __restrict__ Wfc1,
                                                        const float* __restrict__ bfc1,
                                                        const float* __restrict__ Wfc2,
                                                        const float* __restrict__ bfc2,
                                                        float* __restrict__ out,
                                                        float* __restrict__ gsum) {
    __shared__ float facc[BNODES * 8];
    __shared__ float sWrel2[128], sWroot2[128], sbrel2[16];
    __shared__ float sWfc1[512], sbfc1[32], sWfc2[32];
    __shared__ float sbfc2;
    __shared__ float wsum[4];

    int t = threadIdx.x;
    int b = blockIdx.x;
    int gbase = b * BCAP;
    int n0 = b * BNODES;

    for (int k = t; k < BNODES * 8; k += 256) facc[k] = 0.0f;
    if (t < 128) { sWrel2[t] = Wrel2[t]; sWroot2[t] = Wroot2[t]; }
    for (int k = t; k < 512; k += 256) sWfc1[k] = Wfc1[k];
    if (t < 16) sbrel2[t] = brel2[t];
    if (t < 32) { sbfc1[t] = bfc1[t]; sWfc2[t] = Wfc2[t]; }
    if (t == 0) sbfc2 = bfc2[0];
    int C = bucketCnt[b]; if (C > BCAP) C = BCAP;
    __syncthreads();

    int f = t & 7, g = t >> 3;
    for (int e0 = 0; e0 < C; e0 += 64) {
        int e1 = e0 + g, e2 = e1 + 32;
        bool p1 = e1 < C, p2 = e2 < C;
        int v1 = 0, v2 = 0;
        if (p1) v1 = bpay[gbase + e1];
        if (p2) v2 = bpay[gbase + e2];
        if (p1) {
            float val = h1[((v1 & 0x1FFFF) << 3) + f];   // already relu'd
            atomicAdd(&facc[((v1 >> 17) << 3) + f], val);
        }
        if (p2) {
            float val = h1[((v2 & 0x1FFFF) << 3) + f];
            atomicAdd(&facc[((v2 >> 17) << 3) + f], val);
        }
    }
    __syncthreads();

    float o = 0.0f;
    int node = n0 + t;
    if (t < BNODES && node < NN) {
        const float4* hp = (const float4*)(h1 + (size_t)node * 8);
        float4 ha = hp[0], hb = hp[1];
        float h1v[8] = {ha.x, ha.y, ha.z, ha.w, hb.x, hb.y, hb.z, hb.w};
        float s2[8];
#pragma unroll
        for (int j = 0; j < 8; ++j) s2[j] = facc[t * 8 + j];

        float h2[16];
#pragma unroll
        for (int j = 0; j < 16; ++j) h2[j] = sbrel2[j];
#pragma unroll
        for (int k = 0; k < 8; ++k) {
            float sv = s2[k], hv = h1v[k];
#pragma unroll
            for (int j = 0; j < 16; ++j) {
                h2[j] = fmaf(sv, sWrel2[k * 16 + j], h2[j]);
                h2[j] = fmaf(hv, sWroot2[k * 16 + j], h2[j]);
            }
        }
#pragma unroll
        for (int j = 0; j < 16; ++j) h2[j] = h2[j] > 0.0f ? h2[j] : 0.0f;

        o = sbfc2;
#pragma unroll
        for (int m = 0; m < 32; ++m) {
            float a = sbfc1[m];
#pragma unroll
            for (int j = 0; j < 16; ++j) a = fmaf(h2[j], sWfc1[j * 32 + m], a);
            a = a > 0.0f ? a : 0.0f;
            o = fmaf(a, sWfc2[m], o);
        }
        out[node] = o;
    }

    float v = o;
#pragma unroll
    for (int off = 32; off > 0; off >>= 1) v += __shfl_down(v, off);
    int lane = t & 63, w = t >> 6;
    if (lane == 0) wsum[w] = v;
    __syncthreads();
    if (t == 0) atomicAdd(gsum, wsum[0] + wsum[1] + wsum[2] + wsum[3]);
}

__global__ void subtract_mean(float* __restrict__ out,
                              const float* __restrict__ gsum) {
    int i = blockIdx.x * blockDim.x + threadIdx.x;
    if (i < NN) out[i] -= (*gsum) * (1.0f / (float)NN);
}

extern "C" void kernel_launch(void* const* d_in, const int* in_sizes, int n_in,
                              void* d_out, int out_size, void* d_ws, size_t ws_size,
                              hipStream_t stream) {
    const float* x      = (const float*)d_in[0];
    const int*   ei     = (const int*)d_in[1];
    const float* Wrel1  = (const float*)d_in[2];
    const float* brel1  = (const float*)d_in[3];
    const float* Wroot1 = (const float*)d_in[4];
    const float* Wrel2  = (const float*)d_in[5];
    const float* brel2  = (const float*)d_in[6];
    const float* Wroot2 = (const float*)d_in[7];
    const float* Wfc1   = (const float*)d_in[8];
    const float* bfc1   = (const float*)d_in[9];
    const float* Wfc2   = (const float*)d_in[10];
    const float* bfc2   = (const float*)d_in[11];
    float* out = (float*)d_out;
    float* ws  = (float*)d_ws;

    // workspace layout (4-byte units)
    float* y1        = ws;                        // 800000
    float* h1        = ws + 800000;               // 800000 (agg1 init -> relu'd h1)
    int*   bucketCnt = (int*)(ws + 1600000);      // 782
    float* gsum      = ws + 1600782;              // 1
    int*   bpay      = (int*)(ws + 1600783);      // 782*4800 = 3753600 (ends 5354383)

    const int* src = ei;
    const int* dst = ei + NE;

    hipMemsetAsync(bucketCnt, 0, (NBUCK + 1) * sizeof(int), stream);  // + gsum

    node_layer1<<<(NN + 255) / 256, 256, 0, stream>>>(x, Wrel1, brel1, Wroot1, y1, h1);
    binning<<<NBIN_BLOCKS, 512, 0, stream>>>(src, dst, bucketCnt, bpay);
    bucket_agg1<<<NBUCK, 256, 0, stream>>>(bucketCnt, bpay, y1, h1);
    bucket_agg2_tail<<<NBUCK, 256, 0, stream>>>(bucketCnt, bpay, h1,
                                                Wrel2, brel2, Wroot2,
                                                Wfc1, bfc1, Wfc2, bfc2, out, gsum);
    subtract_mean<<<(NN + 255) / 256, 256, 0, stream>>>(out, gsum);
}